// Round 13
// baseline (246.204 us; speedup 1.0000x reference)
//
#include <hip/hip_runtime.h>

typedef __attribute__((ext_vector_type(8))) short bf16x8;
typedef __attribute__((ext_vector_type(8))) unsigned short u16x8;
typedef __attribute__((ext_vector_type(4))) unsigned short u16x4;
typedef __attribute__((ext_vector_type(4))) float f32x4;
typedef unsigned short u16t;

#define MFMA16(a, b, c) __builtin_amdgcn_mfma_f32_16x16x32_bf16((a), (b), (c), 0, 0, 0)
#define GLDS16(gp, lp)                                                        \
  __builtin_amdgcn_global_load_lds(                                           \
      (__attribute__((address_space(1))) void*)(gp),                          \
      (__attribute__((address_space(3))) void*)(lp), 16, 0, 0)

static constexpr float L2E = 1.44269504f;   // log2(e)
static constexpr float MASKV = -1.0e30f;    // finite mask sentinel (no inf paths)

__device__ __forceinline__ u16t f2b(float f) {
  unsigned u = __builtin_bit_cast(unsigned, f);
  u = u + 0x7fffu + ((u >> 16) & 1u); // RNE
  return (u16t)(u >> 16);
}

// ---------------------------------------------------------------------------
// fp32 -> bf16 conversion of x and the 4 weight matrices, one fused launch.
// ---------------------------------------------------------------------------
__global__ void cvt5(const float* __restrict__ x, const float* __restrict__ wq,
                     const float* __restrict__ wk, const float* __restrict__ wv,
                     const float* __restrict__ wo, u16t* __restrict__ xb,
                     u16t* __restrict__ wqb, u16t* __restrict__ wkb,
                     u16t* __restrict__ wvb, u16t* __restrict__ wob) {
  const int bid = blockIdx.x;
  const float* src; u16t* dst; int gb;
  if (bid < 4096)      { src = x;  dst = xb;  gb = bid; }
  else if (bid < 4608) { src = wq; dst = wqb; gb = bid - 4096; }
  else if (bid < 5120) { src = wk; dst = wkb; gb = bid - 4608; }
  else if (bid < 5632) { src = wv; dst = wvb; gb = bid - 5120; }
  else                 { src = wo; dst = wob; gb = bid - 5632; }
  const size_t i = (size_t)gb * 256 + threadIdx.x; // 8-elem group index
  const float4 a = ((const float4*)src)[2 * i];
  const float4 b = ((const float4*)src)[2 * i + 1];
  u16x8 r;
  r[0] = f2b(a.x); r[1] = f2b(a.y); r[2] = f2b(a.z); r[3] = f2b(a.w);
  r[4] = f2b(b.x); r[5] = f2b(b.y); r[6] = f2b(b.z); r[7] = f2b(b.w);
  *(u16x8*)&dst[8 * i] = r;
}

// ---------------------------------------------------------------------------
// GEMM v11 (qkv): unchanged from round 11 (passed, 67.9us, MfmaUtil 31%).
// ---------------------------------------------------------------------------
__global__ void gemm_qkv(const u16t* __restrict__ X,
                         const u16t* __restrict__ Wq, const u16t* __restrict__ Wk,
                         const u16t* __restrict__ Wv,
                         const float* __restrict__ bq, const float* __restrict__ bk,
                         const float* __restrict__ bv,
                         u16t* __restrict__ Qo, u16t* __restrict__ Ko,
                         u16t* __restrict__ Vo) {
  __shared__ __align__(16) u16t SMEM[24576];
  u16t* const As = SMEM;           // [2][128*32]
  u16t* const Bs = SMEM + 8192;    // [2][128*32]
  u16t* const Et = SMEM;           // epilogue tile [128][136]

  const int t = threadIdx.x, lane = t & 63, w = t >> 6;
  const int wr = w >> 1, wc = w & 1, m = lane & 15, quad = lane >> 4;
  const int id = blockIdx.x;
  const int xcd = id & 7, j = id >> 3;
  const int by = xcd * 8 + (j & 7);
  const int rem = j >> 3;                // 0..23
  const int bx = rem & 7, z = rem >> 3;  // bx 0..7, z 0..2
  const int rowBase = by * 128, colBase = bx * 128;
  const u16t* W = (z == 0) ? Wq : ((z == 1) ? Wk : Wv);
  const float* bias = (z == 0) ? bq : ((z == 1) ? bk : bv);
  u16t* Out = (z == 0) ? Qo : ((z == 1) ? Ko : Vo);

  f32x4 acc[4][4];
#pragma unroll
  for (int i = 0; i < 4; i++)
#pragma unroll
    for (int j2 = 0; j2 < 4; j2++) acc[i][j2] = (f32x4){0.f, 0.f, 0.f, 0.f};

  const int lr = lane >> 2, lc = (lane & 3) * 8;
#pragma unroll
  for (int i = 0; i < 2; ++i) {
    const int r0 = i * 64 + w * 16;
    GLDS16(&X[(size_t)(rowBase + r0 + lr) * 1024 + lc], &As[r0 * 32]);
    GLDS16(&W[(size_t)(colBase + r0 + lr) * 1024 + lc], &Bs[r0 * 32]);
  }
  __syncthreads();

  for (int kt = 0; kt < 32; ++kt) {
    const int cur = kt & 1;
    if (kt < 31) {
#pragma unroll
      for (int i = 0; i < 2; ++i) {
        const int r0 = i * 64 + w * 16;
        GLDS16(&X[(size_t)(rowBase + r0 + lr) * 1024 + (kt + 1) * 32 + lc],
               &As[(cur ^ 1) * 4096 + r0 * 32]);
        GLDS16(&W[(size_t)(colBase + r0 + lr) * 1024 + (kt + 1) * 32 + lc],
               &Bs[(cur ^ 1) * 4096 + r0 * 32]);
      }
    }
    bf16x8 af[4], bfr[4];
#pragma unroll
    for (int i = 0; i < 4; i++)
      af[i] = *(const bf16x8*)&As[cur * 4096 + (wr * 64 + i * 16 + m) * 32 + quad * 8];
#pragma unroll
    for (int j2 = 0; j2 < 4; j2++)
      bfr[j2] = *(const bf16x8*)&Bs[cur * 4096 + (wc * 64 + j2 * 16 + m) * 32 + quad * 8];
#pragma unroll
    for (int i = 0; i < 4; i++)
#pragma unroll
      for (int j2 = 0; j2 < 4; j2++) acc[i][j2] = MFMA16(af[i], bfr[j2], acc[i][j2]);
    __syncthreads();
  }

  const int b_ = rowBase >> 10;
  const int sBase0 = rowBase & 1023;
  if (z == 2) {
    const int sBase = sBase0 + wr * 64;
#pragma unroll
    for (int j2 = 0; j2 < 4; j2++) {
      const int col = colBase + wc * 64 + j2 * 16 + m;
      const float bv_ = bias[col];
      const int h = col >> 6, hd = col & 63;
#pragma unroll
      for (int i = 0; i < 4; i++) {
        const int s0 = sBase + i * 16 + quad * 4;
        u16x4 pk;
#pragma unroll
        for (int r = 0; r < 4; r++) pk[r] = f2b(acc[i][j2][r] + bv_);
        *(u16x4*)&Out[(((size_t)b_ * 16 + h) * 64 + hd) * 1024 + s0] = pk;
      }
    }
  } else {
    constexpr int ESTR = 136;
#pragma unroll
    for (int j2 = 0; j2 < 4; j2++) {
      const int cl = wc * 64 + j2 * 16 + m;
      const float bv_ = bias[colBase + cl];
#pragma unroll
      for (int i = 0; i < 4; i++)
#pragma unroll
        for (int r = 0; r < 4; r++)
          Et[(wr * 64 + i * 16 + quad * 4 + r) * ESTR + cl] =
              f2b(acc[i][j2][r] + bv_);
    }
    __syncthreads();
    const int hbase = colBase >> 6;
#pragma unroll
    for (int it = 0; it < 8; ++it) {
      const int chunk = it * 256 + t;
      const int sl = chunk >> 4, c8 = chunk & 15;
      const u16x8 v = *(const u16x8*)&Et[sl * ESTR + c8 * 8];
      const int h2 = hbase + (c8 >> 3), hd0 = (c8 & 7) * 8;
      *(u16x8*)&Out[(((size_t)b_ * 16 + h2) * 1024 + (sBase0 + sl)) * 64 + hd0] = v;
    }
  }
}

__global__ void gemm_o(const u16t* __restrict__ A, const u16t* __restrict__ W,
                       const float* __restrict__ bias, float* __restrict__ Out) {
  __shared__ __align__(16) u16t As[2][128 * 32];
  __shared__ __align__(16) u16t Bs[2][128 * 32];
  const int t = threadIdx.x, lane = t & 63, w = t >> 6;
  const int wr = w >> 1, wc = w & 1, m = lane & 15, quad = lane >> 4;
  const int id = blockIdx.x;
  const int xcd = id & 7, j = id >> 3;
  const int by = xcd * 8 + (j & 7);
  const int bx = j >> 3;
  const int rowBase = by * 128, colBase = bx * 128;

  f32x4 acc[4][4];
#pragma unroll
  for (int i = 0; i < 4; i++)
#pragma unroll
    for (int j2 = 0; j2 < 4; j2++) acc[i][j2] = (f32x4){0.f, 0.f, 0.f, 0.f};

  const int lr = lane >> 2, lc = (lane & 3) * 8;
#pragma unroll
  for (int i = 0; i < 2; ++i) {
    const int r0 = i * 64 + w * 16;
    GLDS16(&A[(size_t)(rowBase + r0 + lr) * 1024 + lc], &As[0][r0 * 32]);
    GLDS16(&W[(size_t)(colBase + r0 + lr) * 1024 + lc], &Bs[0][r0 * 32]);
  }
  __syncthreads();

  for (int kt = 0; kt < 32; ++kt) {
    const int cur = kt & 1;
    if (kt < 31) {
#pragma unroll
      for (int i = 0; i < 2; ++i) {
        const int r0 = i * 64 + w * 16;
        GLDS16(&A[(size_t)(rowBase + r0 + lr) * 1024 + (kt + 1) * 32 + lc],
               &As[cur ^ 1][r0 * 32]);
        GLDS16(&W[(size_t)(colBase + r0 + lr) * 1024 + (kt + 1) * 32 + lc],
               &Bs[cur ^ 1][r0 * 32]);
      }
    }
    bf16x8 af[4], bfr[4];
#pragma unroll
    for (int i = 0; i < 4; i++)
      af[i] = *(const bf16x8*)&As[cur][(wr * 64 + i * 16 + m) * 32 + quad * 8];
#pragma unroll
    for (int j2 = 0; j2 < 4; j2++)
      bfr[j2] = *(const bf16x8*)&Bs[cur][(wc * 64 + j2 * 16 + m) * 32 + quad * 8];
#pragma unroll
    for (int i = 0; i < 4; i++)
#pragma unroll
      for (int j2 = 0; j2 < 4; j2++) acc[i][j2] = MFMA16(af[i], bfr[j2], acc[i][j2]);
    __syncthreads();
  }

#pragma unroll
  for (int j2 = 0; j2 < 4; j2++) {
    const int col = colBase + wc * 64 + j2 * 16 + m;
    const float bv_ = bias[col];
#pragma unroll
    for (int i = 0; i < 4; i++) {
#pragma unroll
      for (int r = 0; r < 4; r++) {
        const int row = rowBase + wr * 64 + i * 16 + quad * 4 + r;
        Out[(size_t)row * 1024 + col] = acc[i][j2][r] + bv_;
      }
    }
  }
}

// ---------------------------------------------------------------------------
// Flash attention v10: TRIPLE-BUFFERED K/V + COUNTED vmcnt + raw s_barrier.
//  r11 analysis: attn wall ~8000 cy/iter vs ~500 issue -> latency-stalled.
//  The dbuf __syncthreads drained vmcnt(0) on the JUST-issued prefetch: a
//  <1-iter window cannot hide an HBM miss (16 bh x (K+V+Q) = 6MB > 4MB L2
//  per XCD -> staging misses to HBM ~900cy) and serializes all 8 waves on
//  the slowest load.
//  New loop: stage(kt+2 -> buf[(kt+2)%3]); compute(kt); vmcnt(2); barrier.
//   - tile kt+1 guaranteed landed a FULL iteration (~1500cy) before its
//     first read (covers HBM); only kt+2's 2 loads stay in flight across
//     the barrier (T4 pattern: never drain to 0 mid-loop).
//   - WAR safe: buf[(kt+2)%3] == buf[(kt-1)%3]; its readers finished
//     before barrier(kt-1), and the GLDS is issued after it.
//   - Collectivization: every wave's vmcnt(2) precedes the shared barrier
//     that precedes the reads of tile kt+1.
//   - Tail (no stage issued): vmcnt(0) instead (last 2 iters only).
//  LDS 66.6KB -> exactly 2 blocks/CU x 256 = 512 blocks resident, uniform.
//  Compute body unchanged (swapped QK^T scalar softmax, verified r9-r11).
// ---------------------------------------------------------------------------
__global__ __launch_bounds__(512) void attn(
    const u16t* __restrict__ Q, const u16t* __restrict__ K,
    const u16t* __restrict__ VT, const int* __restrict__ ids,
    u16t* __restrict__ Oo) {
  constexpr int PSTR = 72;
  __shared__ __align__(16) u16t Kb[3][64 * 64];
  __shared__ __align__(16) u16t Vb[3][64 * 64];
  __shared__ __align__(16) u16t Ps[8][16 * PSTR];
  __shared__ unsigned long long maskL[16];

  const int t = threadIdx.x, lane = t & 63, wl = t >> 6;  // wl: 0..7
  const int m = lane & 15, quad = lane >> 4;
  const int id = blockIdx.x;
  const int g = id & 7, k_ = id >> 3;
  const int bh = g + 8 * (k_ & 15);
  const int p4 = k_ >> 4;                // 0..3
  const int b = bh >> 4, h = bh & 15;
  const size_t hoff = (size_t)bh * 65536;   // 1024 * 64

  const int srow = lane >> 3;
  const int sg = (lane & 7) ^ (srow & 7);

#pragma unroll
  for (int c = 0; c < 2; ++c) {
    const int chunk = wl * 2 + c;
    const int idv = ids[b * 1024 + chunk * 64 + lane];
    const unsigned long long mk = __ballot(idv != 1);
    if (lane == 0) maskL[chunk] = mk;
  }
  __syncthreads();

  u16t* const Pw = &Ps[wl][0];

  for (int pass = 0; pass < 2; ++pass) {
    const int qt8 = pass ? (7 - p4) : p4;
    const int qbase = qt8 * 128 + wl * 16;
    const int qrow = qbase + m;          // this lane's softmax row
    const int ktmax = 2 * qt8 + 1;       // >= 1 always

    // ---- prologue: stage tiles 0 (buf0) and 1 (buf1) ----
    GLDS16(&K[hoff + (size_t)(wl * 8 + srow) * 64 + sg * 8], &Kb[0][wl * 512]);
    GLDS16(&VT[hoff + (size_t)(wl * 8 + srow) * 1024 + sg * 8], &Vb[0][wl * 512]);
    GLDS16(&K[hoff + (size_t)(64 + wl * 8 + srow) * 64 + sg * 8], &Kb[1][wl * 512]);
    GLDS16(&VT[hoff + (size_t)(wl * 8 + srow) * 1024 + 64 + sg * 8], &Vb[1][wl * 512]);

    const bf16x8 qf0 =
        *(const bf16x8*)&Q[hoff + (size_t)(qbase + m) * 64 + quad * 8];
    const bf16x8 qf1 =
        *(const bf16x8*)&Q[hoff + (size_t)(qbase + m) * 64 + 32 + quad * 8];

    float mi = MASKV, li = 0.f;
    f32x4 o[4];
#pragma unroll
    for (int ot = 0; ot < 4; ot++) o[ot] = (f32x4){0.f, 0.f, 0.f, 0.f};

    // tile 0 landed (2 newest outstanding allowed); collectivize
    asm volatile("s_waitcnt vmcnt(2)" ::: "memory");
    __builtin_amdgcn_sched_barrier(0);
    __builtin_amdgcn_s_barrier();
    __builtin_amdgcn_sched_barrier(0);

    for (int kt = 0; kt <= ktmax; ++kt) {
      const int cb = kt % 3;
      const bool more = (kt + 2 <= ktmax);
      if (more) {
        const int nb = (kt + 2) % 3;   // == (kt-1)%3: readers done @bar(kt-1)
        GLDS16(&K[hoff + (size_t)((kt + 2) * 64 + wl * 8 + srow) * 64 + sg * 8],
               &Kb[nb][wl * 512]);
        GLDS16(&VT[hoff + (size_t)(wl * 8 + srow) * 1024 + (kt + 2) * 64 + sg * 8],
               &Vb[nb][wl * 512]);
      }

      if (kt * 64 <= qbase + 15) {       // wave-uniform: any causal work?
        const u16t* const Kc = Kb[cb];
        const u16t* const Vc = Vb[cb];

        const int dq0 = qrow - kt * 64;            // >= 0 inside guard
        const int dqc = dq0 > 63 ? 63 : dq0;
        const unsigned long long causal =
            (dqc == 63) ? ~0ull : ((1ull << (dqc + 1)) - 1ull);
        const unsigned long long km2 = maskL[kt] & causal;
        const unsigned kqlo = (unsigned)(km2 >> (quad * 4));
        const unsigned kqhi = (unsigned)(km2 >> (quad * 4 + 32));

        f32x4 sc[4];
        float pm = MASKV;
#pragma unroll
        for (int nt = 0; nt < 4; nt++) {
          if ((kt * 64 + nt * 16) <= (qbase + 15)) { // wave-uniform skip
            const int krow = (nt * 16 + m) * 64;
            const bf16x8 k0 =
                *(const bf16x8*)&Kc[krow + ((quad ^ (m & 7)) & 7) * 8];
            const bf16x8 k1 =
                *(const bf16x8*)&Kc[krow + (((quad + 4) ^ (m & 7)) & 7) * 8];
            f32x4 c = (f32x4){0.f, 0.f, 0.f, 0.f};
            c = MFMA16(k0, qf0, c);     // SWAPPED: A=K (row=key), B=Q (col=q)
            c = MFMA16(k1, qf1, c);
            const unsigned w32 = (nt < 2) ? kqlo : kqhi;
#pragma unroll
            for (int r = 0; r < 4; r++) {
              const int sh = (nt & 1) * 16 + r;      // compile-time
              const float s = ((w32 >> sh) & 1u) ? c[r] * 0.125f : MASKV;
              sc[nt][r] = s;
              pm = fmaxf(pm, s);
            }
          } else {
#pragma unroll
            for (int r = 0; r < 4; r++) sc[nt][r] = MASKV;
          }
        }
        pm = fmaxf(pm, __shfl_xor(pm, 16));
        pm = fmaxf(pm, __shfl_xor(pm, 32));

        if (__any(pm > mi + 8.0f)) {
          const float mn = (pm > mi + 8.0f) ? pm : mi;
          const float alpha = exp2f((mi - mn) * L2E);
          mi = mn;
          li *= alpha;
#pragma unroll
          for (int r = 0; r < 4; r++) {
            const float ar = __shfl(alpha, quad * 4 + r);
#pragma unroll
            for (int ot = 0; ot < 4; ot++) o[ot][r] *= ar;
          }
        }

        float rsum = 0.f;
#pragma unroll
        for (int nt = 0; nt < 4; nt++) {
          float pf[4];
#pragma unroll
          for (int r = 0; r < 4; r++) {
            pf[r] = exp2f((sc[nt][r] - mi) * L2E);  // masked -> 0
            rsum += pf[r];
          }
          unsigned w0, w1;
          asm("v_cvt_pk_bf16_f32 %0, %1, %2" : "=v"(w0) : "v"(pf[0]), "v"(pf[1]));
          asm("v_cvt_pk_bf16_f32 %0, %1, %2" : "=v"(w1) : "v"(pf[2]), "v"(pf[3]));
          uint2 wv; wv.x = w0; wv.y = w1;
          *(uint2*)&Pw[m * PSTR + nt * 16 + quad * 4] = wv;
        }
        rsum += __shfl_xor(rsum, 16);
        rsum += __shfl_xor(rsum, 32);
        li += rsum;

        const bf16x8 p0 = *(const bf16x8*)&Pw[m * PSTR + quad * 8];
        const bf16x8 p1 = *(const bf16x8*)&Pw[m * PSTR + 32 + quad * 8];
#pragma unroll
        for (int ot = 0; ot < 4; ot++) {
          const int vrow = (ot * 16 + m) * 64;
          const bf16x8 v0 =
              *(const bf16x8*)&Vc[vrow + ((quad ^ (m & 7)) & 7) * 8];
          const bf16x8 v1 =
              *(const bf16x8*)&Vc[vrow + (((quad + 4) ^ (m & 7)) & 7) * 8];
          o[ot] = MFMA16(p0, v0, o[ot]);
          o[ot] = MFMA16(p1, v1, o[ot]);
        }
      }

      // counted wait: tile kt+1 landed; only kt+2's loads cross the barrier
      if (more) {
        asm volatile("s_waitcnt vmcnt(2)" ::: "memory");
      } else {
        asm volatile("s_waitcnt vmcnt(0)" ::: "memory");
      }
      __builtin_amdgcn_sched_barrier(0);
      __builtin_amdgcn_s_barrier();
      __builtin_amdgcn_sched_barrier(0);
    }

    const float linv = (li > 1e-30f) ? 1.f / li : 0.f;
#pragma unroll
    for (int r = 0; r < 4; r++) {
      const float inv = __shfl(linv, quad * 4 + r);
      const int qo = qbase + quad * 4 + r;
#pragma unroll
      for (int ot = 0; ot < 4; ot++) {
        const int col = h * 64 + ot * 16 + m;
        Oo[((size_t)(b * 1024 + qo)) * 1024 + col] = f2b(o[ot][r] * inv);
      }
    }
  }
}

// ---------------------------------------------------------------------------
extern "C" void kernel_launch(void* const* d_in, const int* in_sizes, int n_in,
                              void* d_out, int out_size, void* d_ws, size_t ws_size,
                              hipStream_t stream) {
  const float* x  = (const float*)d_in[0];
  const int*   ids = (const int*)d_in[1];
  const float* Wq = (const float*)d_in[2];
  const float* bq = (const float*)d_in[3];
  const float* Wk = (const float*)d_in[4];
  const float* bk = (const float*)d_in[5];
  const float* Wv = (const float*)d_in[6];
  const float* bv = (const float*)d_in[7];
  const float* Wo = (const float*)d_in[8];
  const float* bo = (const float*)d_in[9];
  float* out = (float*)d_out;

  // ws layout (bf16 elems): XB 8.4M | WqB,WkB,WvB,WoB 1M each | Q,K,V 8.4M each
  u16t* XB  = (u16t*)d_ws;
  u16t* WqB = XB  + 8388608;
  u16t* WkB = WqB + 1048576;
  u16t* WvB = WkB + 1048576;
  u16t* WoB = WvB + 1048576;
  u16t* Qw  = WoB + 1048576;
  u16t* Kw  = Qw  + 8388608;
  u16t* Vw  = Kw  + 8388608;   // holds V^T[b][h][hd][s]
  u16t* AO  = XB; // reuse after gemm_qkv consumed XB

  cvt5<<<6144, 256, 0, stream>>>(x, Wq, Wk, Wv, Wo, XB, WqB, WkB, WvB, WoB);
  gemm_qkv<<<1536, 256, 0, stream>>>(XB, WqB, WkB, WvB, bq, bk, bv, Qw, Kw, Vw);
  attn<<<512, 512, 0, stream>>>(Qw, Kw, Vw, ids, AO);
  gemm_o<<<512, 256, 0, stream>>>(AO, WoB, bo, out);
}